// Round 1
// baseline (176.043 us; speedup 1.0000x reference)
//
#include <hip/hip_runtime.h>
#include <hip/hip_bf16.h>

typedef unsigned short u16;
typedef __attribute__((ext_vector_type(8))) short short8;
typedef __attribute__((ext_vector_type(4))) float f32x4;

#define NROWS 8192   // B*N = 128*64
#define DDIM  256    // feature dim
#define BATCH 64     // epochs per batch item (N)

// ---------------- Kernel 1: L2-normalize rows, f32 -> bf16 ----------------
static __device__ inline u16 f2bf(float x) {
    union { float f; unsigned u; } c; c.f = x;
    unsigned u = c.u;
    unsigned r = (u + 0x7fffu + ((u >> 16) & 1u)) >> 16;  // RNE
    return (u16)r;
}

__global__ __launch_bounds__(256) void norm_kernel(const float* __restrict__ in,
                                                   u16* __restrict__ out) {
    int wave = threadIdx.x >> 6, lane = threadIdx.x & 63;
    int row = blockIdx.x * 4 + wave;                 // 2048 blocks * 4 rows
    const float4* rp = (const float4*)(in + (size_t)row * DDIM);
    float4 v = rp[lane];                             // 64 lanes * 4 = 256
    float ss = v.x * v.x + v.y * v.y + v.z * v.z + v.w * v.w;
    #pragma unroll
    for (int m = 1; m < 64; m <<= 1) ss += __shfl_xor(ss, m, 64);
    float scale = 1.0f / fmaxf(sqrtf(ss), 1e-12f);
    ushort4 o;
    o.x = f2bf(v.x * scale); o.y = f2bf(v.y * scale);
    o.z = f2bf(v.z * scale); o.w = f2bf(v.w * scale);
    ((ushort4*)(out + (size_t)row * DDIM))[lane] = o;
}

// ---------------- Kernel 2: fused Gram + exp + row-sum ----------------
// Tile 128x128, BK=64, 4 waves (2x2), each wave owns a 64x64 sub-tile
// (4x4 fragments of 16x16x32 bf16 MFMA).
__global__ __launch_bounds__(256) void sim_kernel(const u16* __restrict__ f,
                                                  float* __restrict__ tot_acc,
                                                  float* __restrict__ pos_acc) {
    __shared__ u16 lA[128 * 64];   // 16 KB, XOR-swizzled
    __shared__ u16 lB[128 * 64];   // 16 KB

    const int tid  = threadIdx.x;
    const int lane = tid & 63;
    const int wave = tid >> 6;
    const int wr = wave >> 1, wc = wave & 1;
    const int brow = (blockIdx.x >> 6) * 128;   // 64 row tiles
    const int bcol = (blockIdx.x & 63) * 128;   // 64 col tiles

    f32x4 acc[4][4];
    #pragma unroll
    for (int m = 0; m < 4; ++m)
        #pragma unroll
        for (int n = 0; n < 4; ++n)
            acc[m][n] = (f32x4){0.f, 0.f, 0.f, 0.f};

    for (int kt = 0; kt < 4; ++kt) {            // 4 K-steps of 64
        __syncthreads();                        // protect LDS from prev iter readers
        const int kbase = kt * 64;
        #pragma unroll
        for (int i = 0; i < 4; ++i) {
            int o  = (i * 256 + tid) * 16;      // byte offset in 16KB tile
            int r  = o >> 7;                    // row (128B per row)
            int cb = o & 127;                   // byte-in-row
            int sw = r * 128 + (cb ^ ((r & 7) << 4));   // XOR swizzle
            const u16* gA = f + (size_t)(brow + r) * DDIM + kbase + (cb >> 1);
            *(short8*)((char*)lA + sw) = *(const short8*)gA;
            const u16* gB = f + (size_t)(bcol + r) * DDIM + kbase + (cb >> 1);
            *(short8*)((char*)lB + sw) = *(const short8*)gB;
        }
        __syncthreads();
        #pragma unroll
        for (int ks = 0; ks < 2; ++ks) {        // two k=32 MFMA steps
            short8 a[4], b[4];
            const int kb = ks * 64 + ((lane >> 4) << 4);  // byte offset of lane's 8 elems
            #pragma unroll
            for (int m = 0; m < 4; ++m) {
                int rA = wr * 64 + m * 16 + (lane & 15);
                a[m] = *(const short8*)((const char*)lA + rA * 128 + (kb ^ ((rA & 7) << 4)));
                int rB = wc * 64 + m * 16 + (lane & 15);
                b[m] = *(const short8*)((const char*)lB + rB * 128 + (kb ^ ((rB & 7) << 4)));
            }
            #pragma unroll
            for (int m = 0; m < 4; ++m)
                #pragma unroll
                for (int n = 0; n < 4; ++n)
                    acc[m][n] = __builtin_amdgcn_mfma_f32_16x16x32_bf16(a[m], b[n], acc[m][n], 0, 0, 0);
        }
    }

    // ---- epilogue: exp + per-row sums ----
    // C layout: col = lane&15, row = (lane>>4)*4 + j  (m89-verified)
    float rsum[4][4];
    #pragma unroll
    for (int m = 0; m < 4; ++m)
        #pragma unroll
        for (int j = 0; j < 4; ++j) {
            float s = 0.f;
            #pragma unroll
            for (int n = 0; n < 4; ++n) s += __expf(acc[m][n][j]);
            rsum[m][j] = s;
        }
    // reduce across the 16 lanes (lane&15) sharing the same rows
    #pragma unroll
    for (int m = 0; m < 4; ++m)
        #pragma unroll
        for (int j = 0; j < 4; ++j) {
            float s = rsum[m][j];
            s += __shfl_xor(s, 1, 64);
            s += __shfl_xor(s, 2, 64);
            s += __shfl_xor(s, 4, 64);
            s += __shfl_xor(s, 8, 64);
            rsum[m][j] = s;
        }
    // batch index is wave-uniform: rows span exactly one 64-row batch
    const bool diag = ((brow >> 6) + wr) == ((bcol >> 6) + wc);
    if ((lane & 15) == 0) {
        const int g = lane >> 4;
        #pragma unroll
        for (int m = 0; m < 4; ++m)
            #pragma unroll
            for (int j = 0; j < 4; ++j) {
                int row = brow + wr * 64 + m * 16 + g * 4 + j;
                float v = rsum[m][j];
                atomicAdd(&tot_acc[row], v);
                if (diag) atomicAdd(&pos_acc[row], v);
            }
    }
}

// ---------------- Kernel 3: loss = mean(log(total) - log(pos)) ----------------
__global__ __launch_bounds__(256) void loss_kernel(const float* __restrict__ tot,
                                                   const float* __restrict__ pos,
                                                   float* __restrict__ out) {
    __shared__ float red[4];
    int tid = threadIdx.x;
    float s = 0.f;
    for (int r = tid; r < NROWS; r += 256)
        s += logf(tot[r]) - logf(pos[r]);
    #pragma unroll
    for (int m = 1; m < 64; m <<= 1) s += __shfl_xor(s, m, 64);
    if ((tid & 63) == 0) red[tid >> 6] = s;
    __syncthreads();
    if (tid == 0)
        out[0] = (red[0] + red[1] + red[2] + red[3]) * (1.0f / (float)NROWS);
}

extern "C" void kernel_launch(void* const* d_in, const int* in_sizes, int n_in,
                              void* d_out, int out_size, void* d_ws, size_t ws_size,
                              hipStream_t stream) {
    const float* feat = (const float*)d_in[0];
    u16*   f    = (u16*)d_ws;                                    // 8192*256*2 = 4 MB
    float* tot  = (float*)((char*)d_ws + (size_t)NROWS * DDIM * 2);
    float* pos  = tot + NROWS;
    hipMemsetAsync(tot, 0, 2 * NROWS * sizeof(float), stream);
    norm_kernel<<<dim3(NROWS / 4), dim3(256), 0, stream>>>(feat, f);
    sim_kernel<<<dim3(64 * 64), dim3(256), 0, stream>>>(f, tot, pos);
    loss_kernel<<<dim3(1), dim3(256), 0, stream>>>(tot, pos, (float*)d_out);
}

// Round 3
// 103.038 us; speedup vs baseline: 1.7085x; 1.7085x over previous
//
#include <hip/hip_runtime.h>
#include <hip/hip_bf16.h>

typedef unsigned short u16;
typedef __attribute__((ext_vector_type(8))) short short8;
typedef __attribute__((ext_vector_type(4))) float f32x4;

#define NROWS 8192   // B*N = 128*64
#define DDIM  256    // feature dim

// ---------------- Kernel 1: L2-normalize rows, f32 -> bf16 (+ zero accumulators) ----
static __device__ inline u16 f2bf(float x) {
    union { float f; unsigned u; } c; c.f = x;
    unsigned u = c.u;
    unsigned r = (u + 0x7fffu + ((u >> 16) & 1u)) >> 16;  // RNE
    return (u16)r;
}

__global__ __launch_bounds__(256) void norm_kernel(const float* __restrict__ in,
                                                   u16* __restrict__ out,
                                                   float* __restrict__ acc0) {
    int tid = threadIdx.x;
    if (blockIdx.x < 64) acc0[blockIdx.x * 256 + tid] = 0.f;  // zero tot+pos (16384 f32)
    int wave = tid >> 6, lane = tid & 63;
    int row = blockIdx.x * 4 + wave;                 // 2048 blocks * 4 rows
    const float4* rp = (const float4*)(in + (size_t)row * DDIM);
    float4 v = rp[lane];                             // 64 lanes * 4 = 256
    float ss = v.x * v.x + v.y * v.y + v.z * v.z + v.w * v.w;
    #pragma unroll
    for (int m = 1; m < 64; m <<= 1) ss += __shfl_xor(ss, m, 64);
    float scale = 1.0f / fmaxf(sqrtf(ss), 1e-12f);
    ushort4 o;
    o.x = f2bf(v.x * scale); o.y = f2bf(v.y * scale);
    o.z = f2bf(v.z * scale); o.w = f2bf(v.w * scale);
    ((ushort4*)(out + (size_t)row * DDIM))[lane] = o;
}

// ---------------- Kernel 2: fused Gram + exp + row/col-sum (upper triangle) --------
// 2080 blocks = tiles (ti<=tj) of 128x128. BK=64, 4 waves (2x2), each wave a 64x64
// sub-tile (4x4 fragments of 16x16x32 bf16 MFMA). Staging via global_load_lds w=16,
// LDS dest LINEAR + inverse-swizzled global source, swizzled ds_read (rule 21).
__global__ __launch_bounds__(256) void sim_kernel(const u16* __restrict__ f,
                                                  float* __restrict__ tot_acc,
                                                  float* __restrict__ pos_acc) {
    __shared__ u16 lA[128 * 64];   // 16 KB
    __shared__ u16 lB[128 * 64];   // 16 KB

    const int tid  = threadIdx.x;
    const int lane = tid & 63;
    const int wave = tid >> 6;
    const int wr = wave >> 1, wc = wave & 1;

    // decode blockIdx -> (ti, tj), ti <= tj (lower-tri enumeration, swapped)
    int k = blockIdx.x;
    int a = (int)((sqrtf(8.f * (float)k + 1.f) - 1.f) * 0.5f);
    while ((a + 1) * (a + 2) / 2 <= k) ++a;
    while (a * (a + 1) / 2 > k) --a;
    const int ti = k - a * (a + 1) / 2;   // row tile
    const int tj = a;                     // col tile,  ti <= tj
    const int brow = ti * 128, bcol = tj * 128;

    f32x4 acc[4][4];
    #pragma unroll
    for (int m = 0; m < 4; ++m)
        #pragma unroll
        for (int n = 0; n < 4; ++n)
            acc[m][n] = (f32x4){0.f, 0.f, 0.f, 0.f};

    for (int kt = 0; kt < 4; ++kt) {            // 4 K-steps of 64
        __syncthreads();                        // protect LDS from prev-iter readers
        const int kbase = kt * 64;
        #pragma unroll
        for (int i = 0; i < 4; ++i) {
            int o   = (i * 256 + tid) * 16;     // LINEAR LDS byte offset
            int r   = o >> 7;                   // row (128B per row)
            int cb  = o & 127;                  // byte-in-row (dest)
            int scb = cb ^ ((r & 7) << 4);      // inverse-swizzled SOURCE col-byte
            const u16* gA = f + (size_t)(brow + r) * DDIM + kbase + (scb >> 1);
            __builtin_amdgcn_global_load_lds(
                (const __attribute__((address_space(1))) void*)gA,
                (__attribute__((address_space(3))) void*)((char*)lA + o), 16, 0, 0);
            const u16* gB = f + (size_t)(bcol + r) * DDIM + kbase + (scb >> 1);
            __builtin_amdgcn_global_load_lds(
                (const __attribute__((address_space(1))) void*)gB,
                (__attribute__((address_space(3))) void*)((char*)lB + o), 16, 0, 0);
        }
        __syncthreads();                        // drains vmcnt(0): tiles ready
        #pragma unroll
        for (int ks = 0; ks < 2; ++ks) {        // two k=32 MFMA steps
            short8 av[4], bv[4];
            const int kb = ks * 64 + ((lane >> 4) << 4);  // byte offset of lane's 8 elems
            #pragma unroll
            for (int m = 0; m < 4; ++m) {
                int rA = wr * 64 + m * 16 + (lane & 15);
                av[m] = *(const short8*)((const char*)lA + rA * 128 + (kb ^ ((rA & 7) << 4)));
                int rB = wc * 64 + m * 16 + (lane & 15);
                bv[m] = *(const short8*)((const char*)lB + rB * 128 + (kb ^ ((rB & 7) << 4)));
            }
            #pragma unroll
            for (int m = 0; m < 4; ++m)
                #pragma unroll
                for (int n = 0; n < 4; ++n)
                    acc[m][n] = __builtin_amdgcn_mfma_f32_16x16x32_bf16(av[m], bv[n], acc[m][n], 0, 0, 0);
        }
    }

    // ---- epilogue: exp (in place), then row sums (+ col sums for off-diag tiles) ----
    // C layout: col = lane&15, row = (lane>>4)*4 + j  (m89-verified)
    #pragma unroll
    for (int m = 0; m < 4; ++m)
        #pragma unroll
        for (int n = 0; n < 4; ++n)
            #pragma unroll
            for (int j = 0; j < 4; ++j)
                acc[m][n][j] = __expf(acc[m][n][j]);

    // row sums: reduce over n (regs) then over the 16 lanes sharing the rows
    float rs[4][4];
    #pragma unroll
    for (int m = 0; m < 4; ++m)
        #pragma unroll
        for (int j = 0; j < 4; ++j) {
            float s = acc[m][0][j] + acc[m][1][j] + acc[m][2][j] + acc[m][3][j];
            s += __shfl_xor(s, 1, 64);
            s += __shfl_xor(s, 2, 64);
            s += __shfl_xor(s, 4, 64);
            s += __shfl_xor(s, 8, 64);
            rs[m][j] = s;
        }

    if (ti == tj) {
        const bool diag = (wr == wc);           // batch blocks are 64-aligned
        if ((lane & 15) == 0) {
            const int g = lane >> 4;
            #pragma unroll
            for (int m = 0; m < 4; ++m)
                #pragma unroll
                for (int j = 0; j < 4; ++j) {
                    int row = brow + wr * 64 + m * 16 + g * 4 + j;
                    float v = rs[m][j];
                    atomicAdd(&tot_acc[row], v);
                    if (diag) atomicAdd(&pos_acc[row], v);
                }
        }
    } else {
        // col sums: reduce over m,j (regs) then across the 4 row-lane-groups
        float cs[4];
        #pragma unroll
        for (int n = 0; n < 4; ++n) {
            float s = 0.f;
            #pragma unroll
            for (int m = 0; m < 4; ++m)
                #pragma unroll
                for (int j = 0; j < 4; ++j) s += acc[m][n][j];
            s += __shfl_xor(s, 16, 64);
            s += __shfl_xor(s, 32, 64);
            cs[n] = s;
        }
        if ((lane & 15) == 0) {
            const int g = lane >> 4;
            #pragma unroll
            for (int m = 0; m < 4; ++m)
                #pragma unroll
                for (int j = 0; j < 4; ++j)
                    atomicAdd(&tot_acc[brow + wr * 64 + m * 16 + g * 4 + j], rs[m][j]);
        }
        if (lane < 16) {
            #pragma unroll
            for (int n = 0; n < 4; ++n)
                atomicAdd(&tot_acc[bcol + wc * 64 + n * 16 + lane], cs[n]);
        }
    }
}

// ---------------- Kernel 3: loss = mean(log(total) - log(pos)) ----------------
__global__ __launch_bounds__(256) void loss_kernel(const float* __restrict__ tot,
                                                   const float* __restrict__ pos,
                                                   float* __restrict__ out) {
    __shared__ float red[4];
    int tid = threadIdx.x;
    float s = 0.f;
    for (int r = tid; r < NROWS; r += 256)
        s += logf(tot[r]) - logf(pos[r]);
    #pragma unroll
    for (int m = 1; m < 64; m <<= 1) s += __shfl_xor(s, m, 64);
    if ((tid & 63) == 0) red[tid >> 6] = s;
    __syncthreads();
    if (tid == 0)
        out[0] = (red[0] + red[1] + red[2] + red[3]) * (1.0f / (float)NROWS);
}

extern "C" void kernel_launch(void* const* d_in, const int* in_sizes, int n_in,
                              void* d_out, int out_size, void* d_ws, size_t ws_size,
                              hipStream_t stream) {
    const float* feat = (const float*)d_in[0];
    u16*   f    = (u16*)d_ws;                                    // 8192*256*2 = 4 MB
    float* tot  = (float*)((char*)d_ws + (size_t)NROWS * DDIM * 2);
    float* pos  = tot + NROWS;
    norm_kernel<<<dim3(NROWS / 4), dim3(256), 0, stream>>>(feat, f, tot);
    sim_kernel<<<dim3(2080), dim3(256), 0, stream>>>(f, tot, pos);
    loss_kernel<<<dim3(1), dim3(256), 0, stream>>>(tot, pos, (float*)d_out);
}